// Round 5
// baseline (175.931 us; speedup 1.0000x reference)
//
#include <hip/hip_runtime.h>
#include <hip/hip_bf16.h>

// N=16, M=2, T=300, V=25, C=64, KT=9, PAD=4. NM=32, skeletons SK=9600, rows=240000.
// prep -> gcn v6 (1-wave blocks, h direct-to-regs, operand-swapped GEMM1 so the x1t
//                 LDS round-trip is b64/b128 vectorized, direct global D-frag stores)
//      -> conv (4-wave blocks, c-split 16c/wave, shared 72x64 swizzled tile, K=576,
//               BN+ReLU+residual epilogue)  [unchanged from R4 for clean attribution].
//
// Workspace: Y (30.72 MB) | WC2 (73.7 KB) | WGT (8 KB) | A2P (2 KB) | SC/SH (256 B each)

typedef __bf16 bf16x8 __attribute__((ext_vector_type(8)));
typedef __bf16 bf16x4 __attribute__((ext_vector_type(4)));
typedef float  f32x4  __attribute__((ext_vector_type(4)));

#define Y_OFF   0
#define WC2_OFF 30720000
#define WGT_OFF 30793728
#define A2P_OFF 30801920
#define SC_OFF  30803968
#define SH_OFF  30804224

__global__ __launch_bounds__(256) void prep_kernel(
    const float* __restrict__ adj, const float* __restrict__ gcn_w,
    const float* __restrict__ conv_w, const float* __restrict__ conv_b,
    const float* __restrict__ bn_g, const float* __restrict__ bn_b,
    const float* __restrict__ bn_m, const float* __restrict__ bn_v,
    __bf16* __restrict__ wc2, __bf16* __restrict__ wgt,
    __bf16* __restrict__ a2p, float* __restrict__ scale, float* __restrict__ shift) {
  int tid = threadIdx.x;
  // conv weights -> fragment layout: wc2[((kk*4+quad)*64 + c)*8 + j] = w[c][ci][kt],
  // kap = (kk*4+quad)*8 + j = kt*64 + ci (kt-major K index).
  for (int e = blockIdx.x * 256 + tid; e < 36864; e += gridDim.x * 256) {
    int j = e & 7, t1 = e >> 3, c = t1 & 63, g = t1 >> 6;
    int kap = g * 8 + j, kt = kap >> 6, ci = kap & 63;
    wc2[e] = (__bf16)conv_w[(c * 64 + ci) * 9 + kt];
  }
  if (blockIdx.x == 0) {
    for (int e = tid; e < 4096; e += 256) {           // wgt[c][k] = gcn_w[k][c]
      int c = e >> 6, k = e & 63;
      wgt[e] = (__bf16)gcn_w[k * 64 + c];
    }
  } else if (blockIdx.x == 1) {
    for (int e = tid; e < 1024; e += 256) {           // A'' 32x32 zero-padded
      int v = e >> 5, u = e & 31;
      float val = 0.f;
      if (v < 25 && u < 25) {
        float dv = 0.f, du = 0.f;
        for (int t = 0; t < 25; ++t) { dv += adj[v * 25 + t]; du += adj[u * 25 + t]; }
        val = rsqrtf(dv) * adj[v * 25 + u] * rsqrtf(du);
      }
      a2p[e] = (__bf16)val;
    }
  } else if (blockIdx.x == 2) {
    if (tid < 64) {
      float sc = bn_g[tid] * rsqrtf(bn_v[tid] + 1e-5f);
      scale[tid] = sc;
      shift[tid] = (conv_b[tid] - bn_m[tid]) * sc + bn_b[tid];
    }
  }
}

// GCN v6: one skeleton per 1-wave block, barrier-free, 5.1 KB LDS.
// GEMM1 (operands swapped): X1[u][c] = h[u][k] . Wg[k][c]; A-frag = h direct from
// global (u<25 masked), B-frag = Wg (register, L2-hot). D lane = (col=c, rows=4
// consecutive u) -> b64 writes to x1t[c][u] (stride 40). GEMM2: C2[c][v] =
// X1T[c][u] . A''[u][v]; A-frag = b128 x1t reads, B-frag = A'' rows (symmetric,
// registers). Epilogue: bias+ReLU, direct b64 global stores to y[nm][v][t][c].
__global__ __launch_bounds__(64) void gcn_kernel(
    const float* __restrict__ h, const __bf16* __restrict__ wgt_g,
    const __bf16* __restrict__ a2p_g, const float* __restrict__ gcn_b,
    __bf16* __restrict__ y) {
  __shared__ __align__(16) __bf16 x1t[64 * 40];       // [c][u] stride 40 (bank rot 20)
  int lane = threadIdx.x;
  int l15 = lane & 15, quad = lane >> 4;
  int skel = blockIdx.x;                              // 9600 blocks
  int nm = skel / 300, tloc = skel - nm * 300;

  // B-frags for GEMM1: Wg[k][c], lane n=c holds k=quad*8+j (wgt layout [c][k])
  bf16x8 bwg[4][2];
  for (int ct = 0; ct < 4; ++ct)
    for (int kk = 0; kk < 2; ++kk)
      bwg[ct][kk] = *(const bf16x8*)&wgt_g[(ct * 16 + l15) * 64 + kk * 32 + quad * 8];
  // B-frags for GEMM2: A''[u][v], lane n=v holds u=quad*8+j (symmetric -> row v)
  bf16x8 ba[2];
  for (int vt = 0; vt < 2; ++vt)
    ba[vt] = *(const bf16x8*)&a2p_g[(vt * 16 + l15) * 32 + quad * 8];

  // A-frags: h rows direct to registers (fp32 -> bf16), zero for u >= 25
  bf16x8 ah[2][2];
  for (int ut = 0; ut < 2; ++ut) {
    int u = ut * 16 + l15;
    const float* hrow = &h[(skel * 25 + u) * 64];
    for (int kk = 0; kk < 2; ++kk) {
      bf16x8 f = {};
      if (u < 25) {
        float4 p0 = *(const float4*)&hrow[kk * 32 + quad * 8];
        float4 p1 = *(const float4*)&hrow[kk * 32 + quad * 8 + 4];
        f[0] = (__bf16)p0.x; f[1] = (__bf16)p0.y; f[2] = (__bf16)p0.z; f[3] = (__bf16)p0.w;
        f[4] = (__bf16)p1.x; f[5] = (__bf16)p1.y; f[6] = (__bf16)p1.z; f[7] = (__bf16)p1.w;
      }
      ah[ut][kk] = f;
    }
  }
  // GEMM1: M=u(32 pad), N=c(64), K=64
  for (int ut = 0; ut < 2; ++ut)
    for (int ct = 0; ct < 4; ++ct) {
      f32x4 acc = {0.f, 0.f, 0.f, 0.f};
      for (int kk = 0; kk < 2; ++kk)
        acc = __builtin_amdgcn_mfma_f32_16x16x32_bf16(ah[ut][kk], bwg[ct][kk], acc, 0, 0, 0);
      int c = ct * 16 + l15, u0 = ut * 16 + quad * 4;
      bf16x4 p;
      p[0] = (__bf16)acc[0]; p[1] = (__bf16)acc[1];
      p[2] = (__bf16)acc[2]; p[3] = (__bf16)acc[3];
      *(bf16x4*)&x1t[c * 40 + u0] = p;                // b64 write, 4 consecutive u
    }
  // GEMM2: M=c(64), N=v(32 pad), K=u(32); compiler inserts lgkmcnt for the RAW dep
  for (int ct = 0; ct < 4; ++ct) {
    bf16x8 ax = *(const bf16x8*)&x1t[(ct * 16 + l15) * 40 + quad * 8];  // b128
    for (int vt = 0; vt < 2; ++vt) {
      f32x4 acc = {0.f, 0.f, 0.f, 0.f};
      acc = __builtin_amdgcn_mfma_f32_16x16x32_bf16(ax, ba[vt], acc, 0, 0, 0);
      int v = vt * 16 + l15, c0 = ct * 16 + quad * 4;
      if (v < 25) {
        float4 bias = *(const float4*)&gcn_b[c0];
        bf16x4 o;
        o[0] = (__bf16)fmaxf(acc[0] + bias.x, 0.f);
        o[1] = (__bf16)fmaxf(acc[1] + bias.y, 0.f);
        o[2] = (__bf16)fmaxf(acc[2] + bias.z, 0.f);
        o[3] = (__bf16)fmaxf(acc[3] + bias.w, 0.f);
        *(bf16x4*)&y[((nm * 25 + v) * 300 + tloc) * 64 + c0] = o;  // b64 store; L2 merges
      }
    }
  }
}

// Conv v5 (unchanged from R4): 4-wave blocks, shared 72x64 swizzled y tile, c-split:
// wave w owns c [w*16, w*16+16) x 64 t. Per kk: 1 A-frag (global, L2-hot) + 4 B-frags
// (LDS), 4 MFMAs. Epilogue: BN-fold + ReLU + fp32 residual.
__global__ __launch_bounds__(256, 8) void conv_kernel(
    const __bf16* __restrict__ y, const __bf16* __restrict__ wc2,
    const float* __restrict__ scale, const float* __restrict__ shift,
    const float* __restrict__ h, float* __restrict__ out) {
  __shared__ __align__(16) __bf16 my[72 * 64];        // 72 rows x 64c, XOR-swizzled
  int tid = threadIdx.x, w = tid >> 6, lane = tid & 63;
  int l15 = lane & 15, quad = lane >> 4;
  int ti = blockIdx.x, vv = blockIdx.y, nm = blockIdx.z;
  int t0 = (ti < 4) ? ti * 64 : 236;                  // last tile overlaps 20 rows (benign)

  { // cooperative stage: 72 rows x 128 B from y[nm][vv][t0-4 .. t0+67][:]
    const __bf16* ybase = &y[((nm * 25 + vv) * 300) * 64];
    uint4 stg[3];
    for (int it = 0; it < 3; ++it) {
      int idx = it * 256 + tid;
      uint4 val = {0u, 0u, 0u, 0u};
      if (idx < 576) {
        int r = idx >> 3, ch = idx & 7, tg = t0 - 4 + r;
        if (tg >= 0 && tg < 300) val = *(const uint4*)&ybase[tg * 64 + ch * 8];
      }
      stg[it] = val;
    }
    for (int it = 0; it < 3; ++it) {
      int idx = it * 256 + tid;
      if (idx < 576) {
        int r = idx >> 3, ch = idx & 7;
        *(uint4*)&my[r * 64 + ((ch ^ (r & 7)) * 8)] = stg[it];
      }
    }
  }
  __syncthreads();

  f32x4 acc[4];
  for (int n = 0; n < 4; ++n) acc[n] = (f32x4){0.f, 0.f, 0.f, 0.f};

  bf16x8 a0, a1;
#define LOADA(dst, kk_) dst = *(const bf16x8*)&wc2[((((kk_) * 4 + quad) * 64) + w * 16 + l15) * 8];
#define COMPUTE(kk_, areg) { int kt = (kk_) >> 1, chb = ((kk_) & 1) * 4 + quad; \
    for (int n = 0; n < 4; ++n) { \
      int row = n * 16 + l15 + kt; \
      bf16x8 b = *(const bf16x8*)&my[row * 64 + ((chb ^ (row & 7)) * 8)]; \
      acc[n] = __builtin_amdgcn_mfma_f32_16x16x32_bf16(areg, b, acc[n], 0, 0, 0); \
    } }
  LOADA(a0, 0)
  for (int kk = 0; kk < 18; kk += 2) {
    LOADA(a1, kk + 1)
    COMPUTE(kk, a0)
    if (kk + 2 < 18) LOADA(a0, kk + 2)
    COMPUTE(kk + 1, a1)
  }
#undef LOADA
#undef COMPUTE

  int c0 = w * 16 + quad * 4;
  float4 sc = *(const float4*)&scale[c0];
  float4 sh = *(const float4*)&shift[c0];
  for (int n = 0; n < 4; ++n) {
    int tt = t0 + n * 16 + l15;                       // always < 300 by tile choice
    int idx = ((nm * 300 + tt) * 25 + vv) * 64 + c0;
    float4 hr = *(const float4*)&h[idx];
    float4 o;
    o.x = fmaxf(acc[n][0] * sc.x + sh.x, 0.f) + hr.x;
    o.y = fmaxf(acc[n][1] * sc.y + sh.y, 0.f) + hr.y;
    o.z = fmaxf(acc[n][2] * sc.z + sh.z, 0.f) + hr.z;
    o.w = fmaxf(acc[n][3] * sc.w + sh.w, 0.f) + hr.w;
    *(float4*)&out[idx] = o;
  }
}

extern "C" void kernel_launch(void* const* d_in, const int* in_sizes, int n_in,
                              void* d_out, int out_size, void* d_ws, size_t ws_size,
                              hipStream_t stream) {
  const float* h      = (const float*)d_in[0];
  const float* adj    = (const float*)d_in[1];
  const float* gcn_w  = (const float*)d_in[2];
  const float* gcn_b  = (const float*)d_in[3];
  const float* conv_w = (const float*)d_in[4];
  const float* conv_b = (const float*)d_in[5];
  const float* bn_g   = (const float*)d_in[6];
  const float* bn_b   = (const float*)d_in[7];
  const float* bn_m   = (const float*)d_in[8];
  const float* bn_v   = (const float*)d_in[9];
  float* out = (float*)d_out;
  char* ws = (char*)d_ws;

  __bf16* y_ws   = (__bf16*)(ws + Y_OFF);
  __bf16* wc2    = (__bf16*)(ws + WC2_OFF);
  __bf16* wgt    = (__bf16*)(ws + WGT_OFF);
  __bf16* a2p    = (__bf16*)(ws + A2P_OFF);
  float*  scale  = (float*)(ws + SC_OFF);
  float*  shift  = (float*)(ws + SH_OFF);

  prep_kernel<<<64, 256, 0, stream>>>(adj, gcn_w, conv_w, conv_b, bn_g, bn_b, bn_m, bn_v,
                                      wc2, wgt, a2p, scale, shift);
  gcn_kernel<<<9600, 64, 0, stream>>>(h, wgt, a2p, gcn_b, y_ws);
  conv_kernel<<<dim3(5, 25, 32), 256, 0, stream>>>(y_ws, wc2, scale, shift, h, out);
}